// Round 1
// 299.689 us; speedup vs baseline: 1.1088x; 1.1088x over previous
//
#include <hip/hip_runtime.h>
#include <math.h>

// ChebConv2D on MI355X (gfx950).  3-kernel fused pipeline:
//   setup: Cheb mats (pinv via f64 Gauss-Jordan) + weight transposes + zero d
//   k1:    m[b,h,kw,o] = sum_c (sum_w x Tp_w) W_w  (rows in regs), then
//          d[b,kh,kw,o] += sum_{r<4} Tp_h[kh,h0+r] * m_row_r   (atomicAdd)
//   k3:    e[f,kh,kw] = sum_o W_h[o,f,kh] d[b,kh,kw,o];  separable synthesis
//          out[b,f,h,w] = sum_kh Te_h[h,kh] sum_kw e[f,kh,kw] Te_w[w,kw]

#define K9 9

// ---- setup (fused): block 0 builds Cheb mats; blocks 1..450 transpose W + zero d
// Tp = pinv(T) = (T^T T)^-1 T^T  (f64, parallel Gauss-Jordan, no pivot: SPD)
// Wt_w[k][c][o] <- W_w[c][o][k];  Wh_f[f][kh][o] <- W_h[o][f][kh];  d <- 0
__global__ __launch_bounds__(256) void setup_all(const float* __restrict__ Ww,
                                                 const float* __restrict__ Wh,
                                                 float* __restrict__ Tp,
                                                 float* __restrict__ Te,
                                                 float* __restrict__ Tpt16,
                                                 float* __restrict__ Wt_w,
                                                 float* __restrict__ Wh_f,
                                                 float* __restrict__ d_ws) {
    int tid = threadIdx.x;
    if (blockIdx.x != 0) {
        int gid = (blockIdx.x - 1) * 256 + tid;
        if (gid < 36864) {
            int k = gid / 4096, r = gid % 4096, c = r / 64, o = r % 64;
            Wt_w[gid] = Ww[(c * 64 + o) * 9 + k];
        } else if (gid < 73728) {
            int g = gid - 36864;
            int f = g / 576, r = g % 576, kh = r / 64, o = r % 64;
            Wh_f[g] = Wh[(o * 64 + f) * 9 + kh];
        } else if (gid < 115200) {
            int g = gid - 73728;                 // zero d: 165888 floats as float4
            ((float4*)d_ws)[g] = make_float4(0.f, 0.f, 0.f, 0.f);
        }
        return;
    }
    __shared__ double Tsh[128 * K9];
    __shared__ double GA[9][18];   // augmented [G | I] -> [I | G^-1]
    if (tid < 128) {
        int n = tid;
        float xf = (float)((double)n / 127.0);       // np.linspace(0,1,128)
        float xn = 2.0f * xf - 1.0f;
        const float lo = (float)(-1.0 + 1e-6);
        const float hi = (float)(1.0 - 1e-6);
        xn = fminf(fmaxf(xn, lo), hi);
        float th = acosf(xn);
        for (int k = 0; k < K9; ++k) {
            float tv = cosf(th * (float)k);          // f32 like numpy, then f64 cast
            Te[n * K9 + k] = tv;
            Tsh[n * K9 + k] = (double)tv;
        }
    }
    __syncthreads();
    if (tid < 81) {                                   // G = T^T T  (9x9, f64)
        int i = tid / 9, j = tid % 9;
        double s = 0.0;
        for (int n = 0; n < 128; ++n) s += Tsh[n * K9 + i] * Tsh[n * K9 + j];
        GA[i][j] = s;
    }
    if (tid >= 81 && tid < 162) {                     // right half: identity
        int i = (tid - 81) / 9, j = (tid - 81) % 9;
        GA[i][9 + j] = (i == j) ? 1.0 : 0.0;
    }
    __syncthreads();
    int r18 = tid / 18, j18 = tid % 18;
    for (int col = 0; col < 9; ++col) {               // GJ, parallel, no pivot (SPD)
        double inv = 0.0;
        if (tid < 18) inv = 1.0 / GA[col][col];
        __syncthreads();
        if (tid < 18) GA[col][tid] *= inv;
        __syncthreads();
        double f = 0.0;
        if (tid < 162 && r18 != col) f = GA[r18][col];
        __syncthreads();
        if (tid < 162 && r18 != col) GA[r18][j18] -= f * GA[col][j18];
        __syncthreads();
    }
    // Tp[k][n] = sum_j Ginv[k][j] * T[n][j]
    for (int idx = tid; idx < K9 * 128; idx += 256) {
        int k = idx / 128, n = idx % 128;
        double s = 0.0;
        for (int j = 0; j < 9; ++j) s += GA[k][9 + j] * Tsh[n * K9 + j];
        float sv = (float)s;
        Tp[idx] = sv;
        Tpt16[n * 16 + k] = sv;      // transposed, padded row of 16 for s_load
    }
}

// ---------------- K1: x -> d  (width analysis + channel mix + h-analysis) ----
// block = (b, group of 4 h rows), 256 threads.
// Analysis: thread=(row-in-chunk hh2, w-half q, channel c). x staged at stride
// 129 (lane-over-c reads conflict-free). Tp via wave-uniform scalar loads from
// Tpt16; #pragma unroll 8 batches the s_loads so K$ latency hides under FMAs.
// Epilogue: instead of storing m rows, fold the 4 rows into d via 9 kh-weighted
// atomics per (kw,o) column (lane-contiguous addresses -> coalesced atomics).
__global__ __launch_bounds__(256, 2) void k1_width(const float* __restrict__ x,
                                                   const float* __restrict__ Wt_w,
                                                   const float* __restrict__ Tpt16,
                                                   const float* __restrict__ Tp,
                                                   float* __restrict__ d_ws) {
    __shared__ float xs_red[2 * 64 * 129];   // xs [hh2][c][129]; red aliased on top
    __shared__ float cs[4 * 64 * K9];        // coeffs [row][c][k]
    float* xs = xs_red;
    float* red = xs_red;                      // alias: red [wid][c][9] (2304 floats)
    int tid = threadIdx.x;
    int b  = blockIdx.x >> 5;
    int h0 = (blockIdx.x & 31) << 2;
    int c   = tid & 63;
    int wid = tid >> 6;          // 0..3
    int hh2 = wid >> 1;          // row within chunk
    int q   = wid & 1;           // w-half
    int qu  = __builtin_amdgcn_readfirstlane(q);
    const float* tpq = Tpt16 + qu * 64 * 16;
    const float* xb = x + (size_t)b * 1048576;

    for (int ch = 0; ch < 2; ++ch) {
        __syncthreads();                       // protect red/xs from prior readers
        // stage rows h0+2ch, h0+2ch+1 : [hh2s][c][129], b32 writes (2-way, free)
        for (int it = 0; it < 16; ++it) {
            int e = it * 256 + tid;            // float4 index over 2 rows
            int hh2s = e >> 11;
            int e2 = e & 2047;
            int cc = e2 >> 5;
            int w4 = (e2 & 31) << 2;
            float4 v = *(const float4*)(xb + (size_t)cc * 16384 +
                                        (size_t)(h0 + ch * 2 + hh2s) * 128 + w4);
            float* dst = &xs[hh2s * 8256 + cc * 129 + w4];
            dst[0] = v.x; dst[1] = v.y; dst[2] = v.z; dst[3] = v.w;
        }
        __syncthreads();
        // analysis: acc[k] = sum_{w in half} xs[hh2][c][w] * Tp[k][w]
        float acc[K9];
#pragma unroll
        for (int k = 0; k < K9; ++k) acc[k] = 0.f;
        const float* xr = &xs[hh2 * 8256 + c * 129 + qu * 64];
#pragma unroll 8
        for (int w6 = 0; w6 < 64; ++w6) {
            float xv = xr[w6];
            const float* tr = tpq + w6 * 16;   // uniform address -> batched s_load
#pragma unroll
            for (int k = 0; k < K9; ++k) acc[k] = fmaf(xv, tr[k], acc[k]);
        }
        __syncthreads();                       // xs reads done; red may overwrite
        float* rw = &red[(wid * 64 + c) * K9];
#pragma unroll
        for (int k = 0; k < K9; ++k) rw[k] = acc[k];
        __syncthreads();
        // reduce the two w-halves -> cs[row][c][k]
        for (int idx = tid; idx < 2 * 64 * K9; idx += 256) {
            int hh2r = idx / 576, rem = idx - hh2r * 576;
            float v0 = red[(2 * hh2r) * 576 + rem];
            float v1 = red[(2 * hh2r + 1) * 576 + rem];
            cs[(ch * 2 + hh2r) * 576 + rem] = v0 + v1;
        }
    }
    __syncthreads();
    // channel mix + height analysis:
    //   m_r[o][k] = sum_c cs[r][c][k] * Wt_w[k][c][o]   (r = 0..3, in regs)
    //   d[kh][k][o] += sum_r Tp[kh][h0+r] * m_r[o][k]   (atomicAdd, coalesced)
    float* db = d_ws + (size_t)b * 5184;
    const float* tph = Tp + h0;                // Tp[kh*128 + h0 + r]: s_loads
    for (int idx = tid; idx < 576; idx += 256) {
        int o = idx & 63, k = idx >> 6;        // k uniform per wave -> cs broadcast
        const float* wt = Wt_w + k * 4096 + o; // lanes over o: coalesced
        float a0 = 0.f, a1 = 0.f, a2 = 0.f, a3 = 0.f;
        for (int cc = 0; cc < 64; ++cc) {
            float wv = wt[cc * 64];
            float i0 = cs[0 * 576 + cc * 9 + k];
            float i1 = cs[1 * 576 + cc * 9 + k];
            float i2 = cs[2 * 576 + cc * 9 + k];
            float i3 = cs[3 * 576 + cc * 9 + k];
            a0 = fmaf(i0, wv, a0); a1 = fmaf(i1, wv, a1);
            a2 = fmaf(i2, wv, a2); a3 = fmaf(i3, wv, a3);
        }
#pragma unroll
        for (int kh = 0; kh < K9; ++kh) {      // wave-uniform Tp row values
            float t0 = tph[kh * 128 + 0];
            float t1 = tph[kh * 128 + 1];
            float t2 = tph[kh * 128 + 2];
            float t3 = tph[kh * 128 + 3];
            float contrib = fmaf(a0, t0, fmaf(a1, t1, fmaf(a2, t2, a3 * t3)));
            atomicAdd(db + kh * 576 + idx, contrib);   // lanes contiguous in idx
        }
    }
}

// ---------------- K3: d -> out (channel mix + separable synthesis) ----------
// block = (b, f).  e[kh][kw] = sum_o Wh_f[f][kh][o] * d[b][kh][kw][o]
// f1[kh][w] = sum_kw e*Te_w;  out = sum_kh Te_h*f1.
__global__ __launch_bounds__(256) void k3_synth(const float* __restrict__ d_ws,
                                                const float* __restrict__ Wh_f,
                                                const float* __restrict__ Te,
                                                float* __restrict__ out) {
    __shared__ float ds[81 * 65];   // d[b] as [kh*9+kw][o], pad 65 (conflict-free)
    __shared__ float whs[9 * 65];   // Wh_f[f] as [kh][o], pad 65
    __shared__ float tes[1152];     // Te [n][k], stride 9
    __shared__ float f1[9 * 128];
    __shared__ float el[81];
    int tid = threadIdx.x;
    int bf = blockIdx.x;
    int b = bf >> 6, f = bf & 63;
    const float* db = d_ws + (size_t)b * 5184;
    for (int i = tid; i < 5184; i += 256) ds[(i >> 6) * 65 + (i & 63)] = db[i];
    const float* whf = Wh_f + (size_t)f * 576;
    for (int i = tid; i < 576; i += 256) whs[(i >> 6) * 65 + (i & 63)] = whf[i];
    for (int i = tid; i < 1152; i += 256) tes[i] = Te[i];
    __syncthreads();
    if (tid < 81) {                 // e: 81 outputs, sum over o (LDS, 2-way free)
        int kh = tid / 9;
        const float* wr = &whs[kh * 65];
        const float* dr = &ds[tid * 65];
        float ea = 0.f;
#pragma unroll 8
        for (int o = 0; o < 64; ++o) ea = fmaf(wr[o], dr[o], ea);
        el[tid] = ea;
    }
    __syncthreads();
    for (int idx = tid; idx < 1152; idx += 256) {
        int kh = idx >> 7, w = idx & 127;
        float acc = 0.f;
#pragma unroll
        for (int kw = 0; kw < 9; ++kw)
            acc = fmaf(el[kh * 9 + kw], tes[w * 9 + kw], acc);
        f1[kh * 128 + w] = acc;
    }
    __syncthreads();
    int w4 = (tid & 31) << 2;
    int hg = tid >> 5;                 // 0..7
    float4 fr[9];
#pragma unroll
    for (int k = 0; k < 9; ++k) fr[k] = *(const float4*)&f1[k * 128 + w4];
    float* ob = out + (size_t)bf * 16384;
    for (int h = hg; h < 128; h += 8) {
        const float* th = &tes[h * 9];
        float4 acc = make_float4(0.f, 0.f, 0.f, 0.f);
#pragma unroll
        for (int k = 0; k < 9; ++k) {
            float t = th[k];           // broadcast read
            acc.x = fmaf(t, fr[k].x, acc.x);
            acc.y = fmaf(t, fr[k].y, acc.y);
            acc.z = fmaf(t, fr[k].z, acc.z);
            acc.w = fmaf(t, fr[k].w, acc.w);
        }
        *(float4*)(ob + h * 128 + w4) = acc;   // coalesced float4 store
    }
}

extern "C" void kernel_launch(void* const* d_in, const int* in_sizes, int n_in,
                              void* d_out, int out_size, void* d_ws, size_t ws_size,
                              hipStream_t stream) {
    (void)in_sizes; (void)n_in; (void)out_size; (void)ws_size;
    const float* x  = (const float*)d_in[0];
    const float* Ww = (const float*)d_in[1];
    const float* Wh = (const float*)d_in[2];
    float* out = (float*)d_out;
    float* ws = (float*)d_ws;
    // workspace layout (floats): total 243,968 (~976 KB)
    float* Tp    = ws;                        // 1152
    float* Te    = ws + 1152;                 // 1152
    float* Tpt16 = ws + 2304;                 // 2048
    float* Wt_w  = ws + 4352;                 // 36864
    float* Wh_f  = ws + 41216;                // 36864
    float* d_d   = ws + 78080;                // 165888 (16B aligned)

    setup_all<<<451, 256, 0, stream>>>(Ww, Wh, Tp, Te, Tpt16, Wt_w, Wh_f, d_d);
    k1_width<<<1024, 256, 0, stream>>>(x, Wt_w, Tpt16, Tp, d_d);
    k3_synth<<<2048, 256, 0, stream>>>(d_d, Wh_f, Te, out);
}